// Round 1
// baseline (175.855 us; speedup 1.0000x reference)
//
#include <hip/hip_runtime.h>
#include <hip/hip_bf16.h>

// Gather: out[i, :] = table[idx[i], :] for i in [0, 212992), rows of 32 fp32.
// Vectorized as float4: 8 float4 per row, one float4 per thread.
// Consecutive threads in a wave cover consecutive float4s of (mostly) the
// same row -> coalesced stores; row reads are 128B-aligned random accesses
// (2 full 64B lines each, no over-fetch). Index load is an 8-way broadcast.

__global__ __launch_bounds__(256) void gather_rows_f4(
    const int* __restrict__ idx,
    const float4* __restrict__ table,   // table viewed as [vocab, 8] float4
    float4* __restrict__ out,           // out viewed as [n_rows, 8] float4
    int n_vec)                          // total float4 count = n_rows * 8
{
    int t = blockIdx.x * blockDim.x + threadIdx.x;
    if (t >= n_vec) return;
    int row = t >> 3;          // which lookup
    int sub = t & 7;           // which float4 within the 32-float row
    int r = idx[row];          // 8 lanes share this load (L1 broadcast)
    out[t] = table[(size_t)r * 8 + sub];
}

extern "C" void kernel_launch(void* const* d_in, const int* in_sizes, int n_in,
                              void* d_out, int out_size, void* d_ws, size_t ws_size,
                              hipStream_t stream) {
    const int*    idx   = (const int*)d_in[0];     // [4096, 26, 2] int
    const float4* table = (const float4*)d_in[1];  // [1e6, 32] f32 -> [1e6, 8] f4
    float4*       out   = (float4*)d_out;          // [212992, 32] f32 -> f4

    const int n_rows = in_sizes[0];        // 212,992
    const int n_vec  = n_rows * 8;         // 1,703,936 float4s

    const int block = 256;
    const int grid  = (n_vec + block - 1) / block;  // 6656 blocks
    gather_rows_f4<<<grid, block, 0, stream>>>(idx, table, out, n_vec);
}

// Round 3
// 174.810 us; speedup vs baseline: 1.0060x; 1.0060x over previous
//
#include <hip/hip_runtime.h>
#include <hip/hip_bf16.h>

// Gather: out[i, :] = table[idx[i], :], 212,992 rows of 32 fp32 (128 B).
// One float4 per (thread, iteration); 8 lanes cover one row -> coalesced
// stores; table reads are random 128B-aligned segments.
//
// R2: fix compile — __builtin_nontemporal_store needs a clang vector type,
// not HIP's float4 struct. Use ext_vector_type(4) float throughout.
// R1 theory unchanged: 4 float4s per thread, batched loads for 4x MLP to
// hide ~900-cycle random-row latency; nontemporal output stores so the
// 27 MB write-once stream doesn't evict the 128 MB table from L3.

typedef float vfloat4 __attribute__((ext_vector_type(4)));

constexpr int VPT = 4;  // float4s per thread

__global__ __launch_bounds__(256) void gather_rows_f4(
    const int* __restrict__ idx,
    const vfloat4* __restrict__ table,   // [vocab, 8] float4
    vfloat4* __restrict__ out,           // [n_rows, 8] float4
    int n_vec)                           // n_rows * 8
{
    const int t0     = blockIdx.x * blockDim.x + threadIdx.x;
    const int stride = gridDim.x * blockDim.x;

    int  pos[VPT];
    int  r[VPT];
    bool valid[VPT];

    // Phase 1: positions + idx loads (independent, all in flight together)
    int tt = t0;
#pragma unroll
    for (int i = 0; i < VPT; ++i) {
        valid[i] = (tt < n_vec);
        pos[i]   = valid[i] ? tt : 0;
        tt += stride;
    }
#pragma unroll
    for (int i = 0; i < VPT; ++i) {
        r[i] = idx[pos[i] >> 3];        // 8 lanes broadcast-share each row idx
    }

    // Phase 2: 4 independent random table reads in flight
    vfloat4 v[VPT];
#pragma unroll
    for (int i = 0; i < VPT; ++i) {
        v[i] = table[(size_t)r[i] * 8 + (pos[i] & 7)];
    }

    // Phase 3: coalesced nontemporal stores
#pragma unroll
    for (int i = 0; i < VPT; ++i) {
        if (valid[i]) __builtin_nontemporal_store(v[i], &out[pos[i]]);
    }
}

extern "C" void kernel_launch(void* const* d_in, const int* in_sizes, int n_in,
                              void* d_out, int out_size, void* d_ws, size_t ws_size,
                              hipStream_t stream) {
    const int*     idx   = (const int*)d_in[0];      // [4096, 26, 2] int32
    const vfloat4* table = (const vfloat4*)d_in[1];  // [1e6, 32] f32 as [1e6, 8] f4
    vfloat4*       out   = (vfloat4*)d_out;

    const int n_rows = in_sizes[0];                  // 212,992
    const int n_vec  = n_rows * 8;                   // 1,703,936 float4s

    const int block = 256;
    const int grid  = (n_vec + block * VPT - 1) / (block * VPT);  // 1664 blocks
    gather_rows_f4<<<grid, block, 0, stream>>>(idx, table, out, n_vec);
}

// Round 4
// 174.495 us; speedup vs baseline: 1.0078x; 1.0018x over previous
//
#include <hip/hip_runtime.h>
#include <hip/hip_bf16.h>

// Gather: out[i, :] = table[idx[i], :], 212,992 rows of 32 fp32 (128 B).
// 8 lanes per row, one float4 per lane -> coalesced NT stores; table reads
// are random 128B-aligned segments (2 full 64B lines, no over-fetch).
//
// R4: VPT=8 (was 4). 832 blocks / 3328 waves — entire problem resident in
// one wave generation (13 waves/CU), 8 outstanding random row loads per
// thread batched before any store. Grid divides n_vec exactly
// (1,703,936 = 832*256*8) so the valid[] predicates fold away.
// Evidence so far: dur_us has a ~160 us harness-restore floor (500 MB ws
// re-poison ~78 us + 128 MB table restore ~78 us per iteration); kernel
// itself is ~15 us vs ~9-10 us random-gather roofline.

typedef float vfloat4 __attribute__((ext_vector_type(4)));

constexpr int VPT = 8;  // float4s per thread

__global__ __launch_bounds__(256) void gather_rows_f4(
    const int* __restrict__ idx,
    const vfloat4* __restrict__ table,   // [vocab, 8] float4
    vfloat4* __restrict__ out,           // [n_rows, 8] float4
    int n_vec)                           // n_rows * 8
{
    const int t0     = blockIdx.x * blockDim.x + threadIdx.x;
    const int stride = gridDim.x * blockDim.x;

    int  pos[VPT];
    int  r[VPT];
    bool valid[VPT];

    // Phase 1: positions + idx loads (independent, all in flight together)
    int tt = t0;
#pragma unroll
    for (int i = 0; i < VPT; ++i) {
        valid[i] = (tt < n_vec);
        pos[i]   = valid[i] ? tt : 0;
        tt += stride;
    }
#pragma unroll
    for (int i = 0; i < VPT; ++i) {
        r[i] = idx[pos[i] >> 3];        // 8 lanes broadcast-share each row idx
    }

    // Phase 2: 8 independent random table reads in flight
    vfloat4 v[VPT];
#pragma unroll
    for (int i = 0; i < VPT; ++i) {
        v[i] = table[(size_t)r[i] * 8 + (pos[i] & 7)];
    }

    // Phase 3: coalesced nontemporal stores (write-once; don't evict table
    // from L2/L3)
#pragma unroll
    for (int i = 0; i < VPT; ++i) {
        if (valid[i]) __builtin_nontemporal_store(v[i], &out[pos[i]]);
    }
}

extern "C" void kernel_launch(void* const* d_in, const int* in_sizes, int n_in,
                              void* d_out, int out_size, void* d_ws, size_t ws_size,
                              hipStream_t stream) {
    const int*     idx   = (const int*)d_in[0];      // [4096, 26, 2] int32
    const vfloat4* table = (const vfloat4*)d_in[1];  // [1e6, 32] f32 as [1e6, 8] f4
    vfloat4*       out   = (vfloat4*)d_out;

    const int n_rows = in_sizes[0];                  // 212,992
    const int n_vec  = n_rows * 8;                   // 1,703,936 float4s

    const int block = 256;
    const int grid  = (n_vec + block * VPT - 1) / (block * VPT);  // 832 blocks
    gather_rows_f4<<<grid, block, 0, stream>>>(idx, table, out, n_vec);
}